// Round 1
// 712.131 us; speedup vs baseline: 1.1588x; 1.1588x over previous
//
#include <hip/hip_runtime.h>

typedef __attribute__((ext_vector_type(8))) short short8;
typedef __attribute__((ext_vector_type(4))) float f32x4;

#define SS 1024
#define NB 16
#define HROW 72     // bf16 elems per hbuf row (144 B, 16B-aligned)

__device__ __forceinline__ float sigmoidf_(float x) {
    return __builtin_amdgcn_rcpf(1.0f + __expf(-x));
}
__device__ __forceinline__ float tanhf_(float x) {
    return 1.0f - 2.0f * __builtin_amdgcn_rcpf(__expf(2.0f * x) + 1.0f);
}
__device__ __forceinline__ unsigned short f2bf(float f) {   // RNE f32->bf16
    unsigned int u = __float_as_uint(f);
    u += 0x7fffu + ((u >> 16) & 1u);
    return (unsigned short)(u >> 16);
}

// lgkm-only barrier: global (vmcnt) prefetches stay in flight across it.
#define RAW_BARRIER() asm volatile("s_waitcnt lgkmcnt(0)\n\ts_barrier" ::: "memory")

// ============ Kernel 1: x -> bf16 A-fragment-ordered buffer (vectorized) ===
// One short8 output (16 B) per thread; input = 2x float4 contiguous loads.
__global__ __launch_bounds__(256)
void xconv(const float* __restrict__ x, short* __restrict__ xA) {
    const int gid  = blockIdx.x * 256 + threadIdx.x;
    const int half = gid & 1;
    const int q    = (gid >> 1) & 3;
    const int m    = (gid >> 3) & 15;
    const int bt   = gid >> 7;                // bb*1024 + t
    const int t    = bt & 1023;
    const int bb   = bt >> 10;
    const float* __restrict__ xr =
        x + (((size_t)(bb * 16 + m)) * SS + t) * 64 + half * 32 + q * 8;
    const float4 a = *(const float4*)xr;
    const float4 b = *(const float4*)(xr + 4);
    short8 o;
    o[0] = (short)f2bf(a.x); o[1] = (short)f2bf(a.y);
    o[2] = (short)f2bf(a.z); o[3] = (short)f2bf(a.w);
    o[4] = (short)f2bf(b.x); o[5] = (short)f2bf(b.y);
    o[6] = (short)f2bf(b.z); o[7] = (short)f2bf(b.w);
    ((short8*)xA)[gid] = o;
}

// ============ Kernel 2: fused single-group LSTM (4 waves, 1 barrier/step) ==
#define MF(A, Bv, C) __builtin_amdgcn_mfma_f32_16x16x32_bf16(A, Bv, C, 0, 0, 0)

#define LOADB(VAR, G, KC) do {                                                \
    const float* __restrict__ Wsrc = ((KC) < 2) ? rk : wk;                    \
    const int kb = (((KC) & 1) << 5) + (q << 3);                              \
    const int nn = ((G) << 6) + n0;                                           \
    short8 v;                                                                 \
    v[0] = (short)f2bf(Wsrc[(kb + 0) * 256 + nn]);                            \
    v[1] = (short)f2bf(Wsrc[(kb + 1) * 256 + nn]);                            \
    v[2] = (short)f2bf(Wsrc[(kb + 2) * 256 + nn]);                            \
    v[3] = (short)f2bf(Wsrc[(kb + 3) * 256 + nn]);                            \
    v[4] = (short)f2bf(Wsrc[(kb + 4) * 256 + nn]);                            \
    v[5] = (short)f2bf(Wsrc[(kb + 5) * 256 + nn]);                            \
    v[6] = (short)f2bf(Wsrc[(kb + 6) * 256 + nn]);                            \
    v[7] = (short)f2bf(Wsrc[(kb + 7) * 256 + nn]);                            \
    VAR = v; } while (0)

#define XOFF(T) ((((size_t)((bb << 10) | (T))) * 64 + ((m << 2) | q)) * 2)

// One timestep. Reads h_{T-1} from hbuf[PAR^1], writes h_T to hbuf[PAR].
// z-MFMA C-layout puts all 4 gates of (row q*4+j, col n0) in this lane's
// reg j -> gates computed in-register, no z LDS round trip.
// Dense out[T-1] via extra MFMA with B=[dw|0]; wave w stores reg j==w.
// Refills X slot (T&3) with x_{T+4}; consumes XN = x_{T+1} for xpart(T+1).
#define REGION(T, PAR, XC0, XC1, XN0, XN1, DO_O) do {                          \
    const short8 ha0 = *(const short8*)&hbuf[(PAR) ^ 1][m * HROW + (q << 3)];  \
    const short8 ha1 = *(const short8*)&hbuf[(PAR) ^ 1][m * HROW + 32 + (q << 3)]; \
    f32x4 z0 = MF(ha1, BH01, MF(ha0, BH00, xq0));                              \
    f32x4 z1 = MF(ha1, BH11, MF(ha0, BH10, xq1));                              \
    f32x4 z2 = MF(ha1, BH21, MF(ha0, BH20, xq2));                              \
    f32x4 z3 = MF(ha1, BH31, MF(ha0, BH30, xq3));                              \
    if (DO_O) {                                                                \
        const f32x4 zzero = {0.f, 0.f, 0.f, 0.f};                              \
        const f32x4 z4 = MF(ha1, BD1, MF(ha0, BD0, zzero));                    \
        if (m == 0) {                                                          \
            const float zw = (w == 0) ? z4[0] : (w == 1) ? z4[1]               \
                           : (w == 2) ? z4[2] : z4[3];                         \
            out[(size_t)(((bb << 4) + (q << 2) + w) << 10) + (T) - 1] =        \
                sigmoidf_(zw + db0);                                           \
        }                                                                      \
    }                                                                          \
    float h0, h1, h2, h3;                                                      \
    { const float ig = sigmoidf_(z0[0]), fg = sigmoidf_(z1[0]),                \
                  og = sigmoidf_(z3[0]);                                       \
      cc0 = fg * cc0 + ig * tanhf_(z2[0]); h0 = og * tanhf_(cc0); }            \
    { const float ig = sigmoidf_(z0[1]), fg = sigmoidf_(z1[1]),                \
                  og = sigmoidf_(z3[1]);                                       \
      cc1 = fg * cc1 + ig * tanhf_(z2[1]); h1 = og * tanhf_(cc1); }            \
    { const float ig = sigmoidf_(z0[2]), fg = sigmoidf_(z1[2]),                \
                  og = sigmoidf_(z3[2]);                                       \
      cc2 = fg * cc2 + ig * tanhf_(z2[2]); h2 = og * tanhf_(cc2); }            \
    { const float ig = sigmoidf_(z0[3]), fg = sigmoidf_(z1[3]),                \
                  og = sigmoidf_(z3[3]);                                       \
      cc3 = fg * cc3 + ig * tanhf_(z2[3]); h3 = og * tanhf_(cc3); }            \
    hbuf[PAR][((q << 2) + 0) * HROW + n0] = (short)f2bf(h0);                   \
    hbuf[PAR][((q << 2) + 1) * HROW + n0] = (short)f2bf(h1);                   \
    hbuf[PAR][((q << 2) + 2) * HROW + n0] = (short)f2bf(h2);                   \
    hbuf[PAR][((q << 2) + 3) * HROW + n0] = (short)f2bf(h3);                   \
    xq0 = MF(XN1, BX01, MF(XN0, BX00, cb0));                                   \
    xq1 = MF(XN1, BX11, MF(XN0, BX10, cb1));                                   \
    xq2 = MF(XN1, BX21, MF(XN0, BX20, cb2));                                   \
    xq3 = MF(XN1, BX31, MF(XN0, BX30, cb3));                                   \
    { const size_t o = XOFF(((T) + 4 < SS) ? (T) + 4 : SS - 1);                \
      XC0 = xsrc[o]; XC1 = xsrc[o + 1]; }                                      \
    RAW_BARRIER();                                                             \
} while (0)

__global__ __launch_bounds__(256, 1)
void lstm_pipe(const short* __restrict__ xA, const float* __restrict__ wk,
               const float* __restrict__ rk, const float* __restrict__ bias,
               const float* __restrict__ dw, const float* __restrict__ db,
               float* __restrict__ out) {
    const int bb  = blockIdx.x;
    const int tid = threadIdx.x;
    const int l   = tid & 63;
    const int w   = tid >> 6;
    const int m   = l & 15;
    const int q   = l >> 4;
    const int n0  = (w << 4) + m;

    __shared__ short hbuf[2][16 * HROW];      // 4.6 KB, double-buffered h

    for (int i = tid; i < 2 * 16 * HROW; i += 256) ((short*)hbuf)[i] = 0;
    __syncthreads();

    short8 BH00, BH01, BH10, BH11, BH20, BH21, BH30, BH31;
    short8 BX00, BX01, BX10, BX11, BX20, BX21, BX30, BX31;
    LOADB(BH00, 0, 0); LOADB(BH01, 0, 1); LOADB(BX00, 0, 2); LOADB(BX01, 0, 3);
    LOADB(BH10, 1, 0); LOADB(BH11, 1, 1); LOADB(BX10, 1, 2); LOADB(BX11, 1, 3);
    LOADB(BH20, 2, 0); LOADB(BH21, 2, 1); LOADB(BX20, 2, 2); LOADB(BX21, 2, 3);
    LOADB(BH30, 3, 0); LOADB(BH31, 3, 1); LOADB(BX30, 3, 2); LOADB(BX31, 3, 3);

    // Dense B-fragment: column 0 = dw, all other columns 0.
    short8 BD0, BD1;
    {
        short8 v0 = {0, 0, 0, 0, 0, 0, 0, 0}, v1 = v0;
        if (m == 0) {
#pragma unroll
            for (int i = 0; i < 8; ++i) v0[i] = (short)f2bf(dw[(q << 3) + i]);
#pragma unroll
            for (int i = 0; i < 8; ++i) v1[i] = (short)f2bf(dw[32 + (q << 3) + i]);
        }
        BD0 = v0; BD1 = v1;
    }

    const float b0 = bias[n0], b1 = bias[64 + n0];
    const float b2 = bias[128 + n0], b3 = bias[192 + n0];
    const f32x4 cb0 = {b0, b0, b0, b0};
    const f32x4 cb1 = {b1, b1, b1, b1};
    const f32x4 cb2 = {b2, b2, b2, b2};
    const f32x4 cb3 = {b3, b3, b3, b3};
    const float db0 = db[0];

    const short8* __restrict__ xsrc = (const short8*)xA;
    // 4-slot x pipeline: 3 regions of slack covers HBM-miss latency.
    short8 X00 = xsrc[XOFF(0)], X01 = xsrc[XOFF(0) + 1];
    short8 X10 = xsrc[XOFF(1)], X11 = xsrc[XOFF(1) + 1];
    short8 X20 = xsrc[XOFF(2)], X21 = xsrc[XOFF(2) + 1];
    short8 X30 = xsrc[XOFF(3)], X31 = xsrc[XOFF(3) + 1];

    // xpart for t=0
    f32x4 xq0 = MF(X01, BX01, MF(X00, BX00, cb0));
    f32x4 xq1 = MF(X01, BX11, MF(X00, BX10, cb1));
    f32x4 xq2 = MF(X01, BX21, MF(X00, BX20, cb2));
    f32x4 xq3 = MF(X01, BX31, MF(X00, BX30, cb3));

    float cc0 = 0.f, cc1 = 0.f, cc2 = 0.f, cc3 = 0.f;

    REGION(0, 0, X00, X01, X10, X11, 0);
    REGION(1, 1, X10, X11, X20, X21, 1);
    REGION(2, 0, X20, X21, X30, X31, 1);
    REGION(3, 1, X30, X31, X00, X01, 1);
    for (int t = 4; t < SS; t += 4) {
        REGION(t,     0, X00, X01, X10, X11, 1);
        REGION(t + 1, 1, X10, X11, X20, X21, 1);
        REGION(t + 2, 0, X20, X21, X30, X31, 1);
        REGION(t + 3, 1, X30, X31, X00, X01, 1);
    }
    // Epilogue: dense for h_{SS-1} (sits in hbuf[1] after final barrier).
    {
        const short8 ha0 = *(const short8*)&hbuf[1][m * HROW + (q << 3)];
        const short8 ha1 = *(const short8*)&hbuf[1][m * HROW + 32 + (q << 3)];
        const f32x4 zzero = {0.f, 0.f, 0.f, 0.f};
        const f32x4 z4 = MF(ha1, BD1, MF(ha0, BD0, zzero));
        if (m == 0) {
            const float zw = (w == 0) ? z4[0] : (w == 1) ? z4[1]
                           : (w == 2) ? z4[2] : z4[3];
            out[(size_t)(((bb << 4) + (q << 2) + w) << 10) + SS - 1] =
                sigmoidf_(zw + db0);
        }
    }
}

// ============ Host ============
extern "C" void kernel_launch(void* const* d_in, const int* in_sizes, int n_in,
                              void* d_out, int out_size, void* d_ws, size_t ws_size,
                              hipStream_t stream) {
    const float* x    = (const float*)d_in[0];
    const float* wk   = (const float*)d_in[1];
    const float* rk   = (const float*)d_in[2];
    const float* bias = (const float*)d_in[3];
    const float* dw   = (const float*)d_in[4];
    const float* db   = (const float*)d_in[5];
    float* out = (float*)d_out;

    short* xA = (short*)d_ws;   // 16*1024*128 short8 = 33.5 MB

    hipLaunchKernelGGL(xconv, dim3(NB * 1024 * 128 / 256), dim3(256), 0, stream,
                       x, xA);
    hipLaunchKernelGGL(lstm_pipe, dim3(NB), dim3(256), 0, stream,
                       xA, wk, rk, bias, dw, db, out);
}

// Round 2
// 500.567 us; speedup vs baseline: 1.6486x; 1.4226x over previous
//
#include <hip/hip_runtime.h>

typedef __attribute__((ext_vector_type(8))) short short8;
typedef __attribute__((ext_vector_type(4))) float f32x4;

#define SS 1024
#define NB 16      // xconv macroblocks (16 rows each)
#define NBLK 32    // lstm blocks (8 rows each)
#define HROW 72    // bf16 elems per hbuf row (144 B, 16B-aligned)

__device__ __forceinline__ float sigmoidf_(float x) {
    return __builtin_amdgcn_rcpf(1.0f + __expf(-x));
}
__device__ __forceinline__ float tanhf_(float x) {
    return 1.0f - 2.0f * __builtin_amdgcn_rcpf(__expf(2.0f * x) + 1.0f);
}
__device__ __forceinline__ unsigned short f2bf(float f) {   // RNE f32->bf16
    unsigned int u = __float_as_uint(f);
    u += 0x7fffu + ((u >> 16) & 1u);
    return (unsigned short)(u >> 16);
}

// lgkm-only barrier: global (vmcnt) prefetches stay in flight across it.
#define RAW_BARRIER() asm volatile("s_waitcnt lgkmcnt(0)\n\ts_barrier" ::: "memory")

// ============ Kernel 1: x -> bf16 A-fragment-ordered buffer (vectorized) ===
__global__ __launch_bounds__(256)
void xconv(const float* __restrict__ x, short* __restrict__ xA) {
    const int gid  = blockIdx.x * 256 + threadIdx.x;
    const int half = gid & 1;
    const int q    = (gid >> 1) & 3;
    const int m    = (gid >> 3) & 15;
    const int bt   = gid >> 7;                // mb*1024 + t
    const int t    = bt & 1023;
    const int mb   = bt >> 10;
    const float* __restrict__ xr =
        x + (((size_t)(mb * 16 + m)) * SS + t) * 64 + half * 32 + q * 8;
    const float4 a = *(const float4*)xr;
    const float4 b = *(const float4*)(xr + 4);
    short8 o;
    o[0] = (short)f2bf(a.x); o[1] = (short)f2bf(a.y);
    o[2] = (short)f2bf(a.z); o[3] = (short)f2bf(a.w);
    o[4] = (short)f2bf(b.x); o[5] = (short)f2bf(b.y);
    o[6] = (short)f2bf(b.z); o[7] = (short)f2bf(b.w);
    ((short8*)xA)[gid] = o;
}

// ============ Kernel 2: 8-row sparse-A fused LSTM (32 blocks) ==============
// Batch rows 0..7 of this block map to A-rows {0,1,4,5,8,9,12,13}. MFMA C
// layout (row = q*4+reg) then puts the two real rows of every lane group in
// regs 0,1 -> every lane computes exactly 2 gate sets, no cross-lane moves.
// Pad A-rows read zeros from hbuf (never written) and duplicated x (unused).
#define MF(A, Bv, C) __builtin_amdgcn_mfma_f32_16x16x32_bf16(A, Bv, C, 0, 0, 0)

#define LOADB(VAR, G, KC) do {                                                \
    const float* __restrict__ Wsrc = ((KC) < 2) ? rk : wk;                    \
    const int kb = (((KC) & 1) << 5) + (q << 3);                              \
    const int nn = ((G) << 6) + n0;                                           \
    short8 v;                                                                 \
    v[0] = (short)f2bf(Wsrc[(kb + 0) * 256 + nn]);                            \
    v[1] = (short)f2bf(Wsrc[(kb + 1) * 256 + nn]);                            \
    v[2] = (short)f2bf(Wsrc[(kb + 2) * 256 + nn]);                            \
    v[3] = (short)f2bf(Wsrc[(kb + 3) * 256 + nn]);                            \
    v[4] = (short)f2bf(Wsrc[(kb + 4) * 256 + nn]);                            \
    v[5] = (short)f2bf(Wsrc[(kb + 5) * 256 + nn]);                            \
    v[6] = (short)f2bf(Wsrc[(kb + 6) * 256 + nn]);                            \
    v[7] = (short)f2bf(Wsrc[(kb + 7) * 256 + nn]);                            \
    VAR = v; } while (0)

// xA index (short8 units) for this lane's A-row at timestep T
#define XIDX(T) (xb0 + ((size_t)(T) << 7))

// Order: issue ha reads + x refill first, then independent next-step x-part
// MFMAs (covers LDS latency), then z MFMAs, gates, h write, barrier.
#define REGION(T, PAR, XC0, XC1, XN0, XN1, QC0, QC1, QC2, QC3,                 \
               QN0, QN1, QN2, QN3, DO_O) do {                                  \
    const short8 ha0 = *(const short8*)&hbuf[(PAR) ^ 1][m * HROW + (q << 3)];  \
    const short8 ha1 = *(const short8*)&hbuf[(PAR) ^ 1][m * HROW + 32 + (q << 3)]; \
    { const size_t o = XIDX(((T) + 4 < SS) ? (T) + 4 : SS - 1);                \
      XC0 = xsrc[o]; XC1 = xsrc[o + 1]; }                                      \
    QN0 = MF(XN1, BX01, MF(XN0, BX00, cb0));                                   \
    QN1 = MF(XN1, BX11, MF(XN0, BX10, cb1));                                   \
    QN2 = MF(XN1, BX21, MF(XN0, BX20, cb2));                                   \
    QN3 = MF(XN1, BX31, MF(XN0, BX30, cb3));                                   \
    const f32x4 z0 = MF(ha1, BH01, MF(ha0, BH00, QC0));                        \
    const f32x4 z1 = MF(ha1, BH11, MF(ha0, BH10, QC1));                        \
    const f32x4 z2 = MF(ha1, BH21, MF(ha0, BH20, QC2));                        \
    const f32x4 z3 = MF(ha1, BH31, MF(ha0, BH30, QC3));                        \
    if (DO_O) {                                                                \
        const f32x4 zzero = {0.f, 0.f, 0.f, 0.f};                              \
        const f32x4 z4 = MF(ha1, BD1, MF(ha0, BD0, zzero));                    \
        if (m == 0 && w < 2) {                                                 \
            const float zw = (w == 0) ? z4[0] : z4[1];                         \
            out[((size_t)((bb << 3) + (q << 1) + w) << 10) + (T) - 1] =        \
                sigmoidf_(zw + db0);                                           \
        }                                                                      \
    }                                                                          \
    float h0, h1;                                                              \
    { const float ig = sigmoidf_(z0[0]), fg = sigmoidf_(z1[0]),                \
                  og = sigmoidf_(z3[0]);                                       \
      cc0 = fg * cc0 + ig * tanhf_(z2[0]); h0 = og * tanhf_(cc0); }            \
    { const float ig = sigmoidf_(z0[1]), fg = sigmoidf_(z1[1]),                \
                  og = sigmoidf_(z3[1]);                                       \
      cc1 = fg * cc1 + ig * tanhf_(z2[1]); h1 = og * tanhf_(cc1); }            \
    hbuf[PAR][((q << 2) + 0) * HROW + n0] = (short)f2bf(h0);                   \
    hbuf[PAR][((q << 2) + 1) * HROW + n0] = (short)f2bf(h1);                   \
    RAW_BARRIER();                                                             \
} while (0)

__global__ __launch_bounds__(256, 1)
void lstm_pipe(const short* __restrict__ xA, const float* __restrict__ wk,
               const float* __restrict__ rk, const float* __restrict__ bias,
               const float* __restrict__ dw, const float* __restrict__ db,
               float* __restrict__ out) {
    const int bb  = blockIdx.x;               // 0..31, 8 batch rows each
    const int tid = threadIdx.x;
    const int l   = tid & 63;
    const int w   = tid >> 6;
    const int m   = l & 15;
    const int q   = l >> 4;
    const int n0  = (w << 4) + m;

    __shared__ short hbuf[2][16 * HROW];      // 4.6 KB, double-buffered h

    for (int i = tid; i < 2 * 16 * HROW; i += 256) ((short*)hbuf)[i] = 0;
    __syncthreads();

    short8 BH00, BH01, BH10, BH11, BH20, BH21, BH30, BH31;
    short8 BX00, BX01, BX10, BX11, BX20, BX21, BX30, BX31;
    LOADB(BH00, 0, 0); LOADB(BH01, 0, 1); LOADB(BX00, 0, 2); LOADB(BX01, 0, 3);
    LOADB(BH10, 1, 0); LOADB(BH11, 1, 1); LOADB(BX10, 1, 2); LOADB(BX11, 1, 3);
    LOADB(BH20, 2, 0); LOADB(BH21, 2, 1); LOADB(BX20, 2, 2); LOADB(BX21, 2, 3);
    LOADB(BH30, 3, 0); LOADB(BH31, 3, 1); LOADB(BX30, 3, 2); LOADB(BX31, 3, 3);

    // Dense B-fragment: column 0 = dw, all other columns 0.
    short8 BD0, BD1;
    {
        short8 v0 = {0, 0, 0, 0, 0, 0, 0, 0}, v1 = v0;
        if (m == 0) {
#pragma unroll
            for (int i = 0; i < 8; ++i) v0[i] = (short)f2bf(dw[(q << 3) + i]);
#pragma unroll
            for (int i = 0; i < 8; ++i) v1[i] = (short)f2bf(dw[32 + (q << 3) + i]);
        }
        BD0 = v0; BD1 = v1;
    }

    const float b0 = bias[n0], b1 = bias[64 + n0];
    const float b2 = bias[128 + n0], b3 = bias[192 + n0];
    const f32x4 cb0 = {b0, b0, b0, b0};
    const f32x4 cb1 = {b1, b1, b1, b1};
    const f32x4 cb2 = {b2, b2, b2, b2};
    const f32x4 cb3 = {b3, b3, b3, b3};
    const float db0 = db[0];

    // x addressing: A-row m <- batch row br = 2*(m>>2) + (m&1) (pad lanes
    // m&2==1 duplicate a real row; their z regs 2,3 are never consumed).
    const int mb  = bb >> 1;
    const int br  = ((m >> 2) << 1) | (m & 1);
    const int l16 = ((bb & 1) << 3) | br;     // row within 16-row macroblock
    const size_t xb0 = (size_t)mb * 131072 + (size_t)(((l16 << 2) | q) << 1);

    const short8* __restrict__ xsrc = (const short8*)xA;
    short8 X00 = xsrc[XIDX(0)], X01 = xsrc[XIDX(0) + 1];
    short8 X10 = xsrc[XIDX(1)], X11 = xsrc[XIDX(1) + 1];
    short8 X20 = xsrc[XIDX(2)], X21 = xsrc[XIDX(2) + 1];
    short8 X30 = xsrc[XIDX(3)], X31 = xsrc[XIDX(3) + 1];

    // xpart for t=0 (set A)
    f32x4 qA0 = MF(X01, BX01, MF(X00, BX00, cb0));
    f32x4 qA1 = MF(X01, BX11, MF(X00, BX10, cb1));
    f32x4 qA2 = MF(X01, BX21, MF(X00, BX20, cb2));
    f32x4 qA3 = MF(X01, BX31, MF(X00, BX30, cb3));
    f32x4 qB0, qB1, qB2, qB3;

    float cc0 = 0.f, cc1 = 0.f;

    REGION(0, 0, X00, X01, X10, X11, qA0, qA1, qA2, qA3, qB0, qB1, qB2, qB3, 0);
    REGION(1, 1, X10, X11, X20, X21, qB0, qB1, qB2, qB3, qA0, qA1, qA2, qA3, 1);
    REGION(2, 0, X20, X21, X30, X31, qA0, qA1, qA2, qA3, qB0, qB1, qB2, qB3, 1);
    REGION(3, 1, X30, X31, X00, X01, qB0, qB1, qB2, qB3, qA0, qA1, qA2, qA3, 1);
    for (int t = 4; t < SS; t += 4) {
        REGION(t,     0, X00, X01, X10, X11, qA0, qA1, qA2, qA3, qB0, qB1, qB2, qB3, 1);
        REGION(t + 1, 1, X10, X11, X20, X21, qB0, qB1, qB2, qB3, qA0, qA1, qA2, qA3, 1);
        REGION(t + 2, 0, X20, X21, X30, X31, qA0, qA1, qA2, qA3, qB0, qB1, qB2, qB3, 1);
        REGION(t + 3, 1, X30, X31, X00, X01, qB0, qB1, qB2, qB3, qA0, qA1, qA2, qA3, 1);
    }
    // Epilogue: dense for h_{SS-1} (in hbuf[1] after the final barrier).
    {
        const short8 ha0 = *(const short8*)&hbuf[1][m * HROW + (q << 3)];
        const short8 ha1 = *(const short8*)&hbuf[1][m * HROW + 32 + (q << 3)];
        const f32x4 zzero = {0.f, 0.f, 0.f, 0.f};
        const f32x4 z4 = MF(ha1, BD1, MF(ha0, BD0, zzero));
        if (m == 0 && w < 2) {
            const float zw = (w == 0) ? z4[0] : z4[1];
            out[((size_t)((bb << 3) + (q << 1) + w) << 10) + SS - 1] =
                sigmoidf_(zw + db0);
        }
    }
}

// ============ Host ============
extern "C" void kernel_launch(void* const* d_in, const int* in_sizes, int n_in,
                              void* d_out, int out_size, void* d_ws, size_t ws_size,
                              hipStream_t stream) {
    const float* x    = (const float*)d_in[0];
    const float* wk   = (const float*)d_in[1];
    const float* rk   = (const float*)d_in[2];
    const float* bias = (const float*)d_in[3];
    const float* dw   = (const float*)d_in[4];
    const float* db   = (const float*)d_in[5];
    float* out = (float*)d_out;

    short* xA = (short*)d_ws;   // 16*1024*128 short8 = 33.5 MB

    hipLaunchKernelGGL(xconv, dim3(NB * 1024 * 128 / 256), dim3(256), 0, stream,
                       x, xA);
    hipLaunchKernelGGL(lstm_pipe, dim3(NBLK), dim3(256), 0, stream,
                       xA, wk, rk, bias, dw, db, out);
}

// Round 3
// 437.189 us; speedup vs baseline: 1.8876x; 1.1450x over previous
//
#include <hip/hip_runtime.h>

typedef __attribute__((ext_vector_type(8))) short short8;
typedef __attribute__((ext_vector_type(4))) float f32x4;

#define SS 1024
#define NB 16      // xconv macroblocks (16 rows each)
#define NBLK 64    // lstm blocks (4 rows each)
#define HROW 72    // bf16 elems per hbuf row (144 B, 16B-aligned)

__device__ __forceinline__ float sigmoidf_(float x) {
    return __builtin_amdgcn_rcpf(1.0f + __expf(-x));
}
__device__ __forceinline__ float tanhf_(float x) {
    return 1.0f - 2.0f * __builtin_amdgcn_rcpf(__expf(2.0f * x) + 1.0f);
}
__device__ __forceinline__ unsigned short f2bf(float f) {   // RNE f32->bf16
    unsigned int u = __float_as_uint(f);
    u += 0x7fffu + ((u >> 16) & 1u);
    return (unsigned short)(u >> 16);
}

// lgkm-only barrier: global (vmcnt) prefetches stay in flight across it.
#define RAW_BARRIER() asm volatile("s_waitcnt lgkmcnt(0)\n\ts_barrier" ::: "memory")

// ============ Kernel 1: x -> bf16 A-fragment-ordered buffer (vectorized) ===
__global__ __launch_bounds__(256)
void xconv(const float* __restrict__ x, short* __restrict__ xA) {
    const int gid  = blockIdx.x * 256 + threadIdx.x;
    const int half = gid & 1;
    const int q    = (gid >> 1) & 3;
    const int m    = (gid >> 3) & 15;
    const int bt   = gid >> 7;                // mb*1024 + t
    const int t    = bt & 1023;
    const int mb   = bt >> 10;
    const float* __restrict__ xr =
        x + (((size_t)(mb * 16 + m)) * SS + t) * 64 + half * 32 + q * 8;
    const float4 a = *(const float4*)xr;
    const float4 b = *(const float4*)(xr + 4);
    short8 o;
    o[0] = (short)f2bf(a.x); o[1] = (short)f2bf(a.y);
    o[2] = (short)f2bf(a.z); o[3] = (short)f2bf(a.w);
    o[4] = (short)f2bf(b.x); o[5] = (short)f2bf(b.y);
    o[6] = (short)f2bf(b.z); o[7] = (short)f2bf(b.w);
    ((short8*)xA)[gid] = o;
}

// ============ Kernel 2: 4-row sparse-A fused LSTM (64 blocks) ==============
// Batch row b (0..3) of this block maps to A-row 4b; A-rows 4b+1..3 are pads
// (duplicated x, zero h -> finite garbage, discarded). MFMA C layout
// (row = q*4+reg) then puts the single real row of every lane group in reg 0
// -> every lane computes exactly 1 gate set (batch q, col n0).
#define MF(A, Bv, C) __builtin_amdgcn_mfma_f32_16x16x32_bf16(A, Bv, C, 0, 0, 0)

#define LOADB(VAR, G, KC) do {                                                \
    const float* __restrict__ Wsrc = ((KC) < 2) ? rk : wk;                    \
    const int kb = (((KC) & 1) << 5) + (q << 3);                              \
    const int nn = ((G) << 6) + n0;                                           \
    short8 v;                                                                 \
    v[0] = (short)f2bf(Wsrc[(kb + 0) * 256 + nn]);                            \
    v[1] = (short)f2bf(Wsrc[(kb + 1) * 256 + nn]);                            \
    v[2] = (short)f2bf(Wsrc[(kb + 2) * 256 + nn]);                            \
    v[3] = (short)f2bf(Wsrc[(kb + 3) * 256 + nn]);                            \
    v[4] = (short)f2bf(Wsrc[(kb + 4) * 256 + nn]);                            \
    v[5] = (short)f2bf(Wsrc[(kb + 5) * 256 + nn]);                            \
    v[6] = (short)f2bf(Wsrc[(kb + 6) * 256 + nn]);                            \
    v[7] = (short)f2bf(Wsrc[(kb + 7) * 256 + nn]);                            \
    VAR = v; } while (0)

// xA index (short8 units) for this lane's A-row at timestep T
#define XIDX(T) (xb0 + ((size_t)(T) << 7))

// Order: ha reads + x refill first, then independent next-step x-part MFMAs
// (cover LDS latency), then z MFMAs, gates (reg 0 only), h write, barrier.
#define REGION(T, PAR, XC0, XC1, XN0, XN1, QC0, QC1, QC2, QC3,                 \
               QN0, QN1, QN2, QN3, DO_O) do {                                  \
    const short8 ha0 = *(const short8*)&hbuf[(PAR) ^ 1][m * HROW + (q << 3)];  \
    const short8 ha1 = *(const short8*)&hbuf[(PAR) ^ 1][m * HROW + 32 + (q << 3)]; \
    { const size_t o = XIDX(((T) + 4 < SS) ? (T) + 4 : SS - 1);                \
      XC0 = xsrc[o]; XC1 = xsrc[o + 1]; }                                      \
    QN0 = MF(XN1, BX01, MF(XN0, BX00, cb0));                                   \
    QN1 = MF(XN1, BX11, MF(XN0, BX10, cb1));                                   \
    QN2 = MF(XN1, BX21, MF(XN0, BX20, cb2));                                   \
    QN3 = MF(XN1, BX31, MF(XN0, BX30, cb3));                                   \
    const f32x4 z0 = MF(ha1, BH01, MF(ha0, BH00, QC0));                        \
    const f32x4 z1 = MF(ha1, BH11, MF(ha0, BH10, QC1));                        \
    const f32x4 z2 = MF(ha1, BH21, MF(ha0, BH20, QC2));                        \
    const f32x4 z3 = MF(ha1, BH31, MF(ha0, BH30, QC3));                        \
    if ((DO_O) && w == 0) {                                                    \
        const f32x4 zzero = {0.f, 0.f, 0.f, 0.f};                              \
        const f32x4 z4 = MF(ha1, BD1, MF(ha0, BD0, zzero));                    \
        if (m == 0) {                                                          \
            out[((size_t)((bb << 2) + q) << 10) + (T) - 1] =                   \
                sigmoidf_(z4[0] + db0);                                        \
        }                                                                      \
    }                                                                          \
    { const float ig = sigmoidf_(z0[0]), fg = sigmoidf_(z1[0]),                \
                  og = sigmoidf_(z3[0]);                                       \
      cc0 = fg * cc0 + ig * tanhf_(z2[0]);                                     \
      const float h0 = og * tanhf_(cc0);                                       \
      hbuf[PAR][(q << 2) * HROW + n0] = (short)f2bf(h0); }                     \
    RAW_BARRIER();                                                             \
} while (0)

__global__ __launch_bounds__(256, 1)
void lstm_pipe(const short* __restrict__ xA, const float* __restrict__ wk,
               const float* __restrict__ rk, const float* __restrict__ bias,
               const float* __restrict__ dw, const float* __restrict__ db,
               float* __restrict__ out) {
    const int bb  = blockIdx.x;               // 0..63, 4 batch rows each
    const int tid = threadIdx.x;
    const int l   = tid & 63;
    const int w   = tid >> 6;
    const int m   = l & 15;
    const int q   = l >> 4;
    const int n0  = (w << 4) + m;

    __shared__ short hbuf[2][16 * HROW];      // 4.6 KB, double-buffered h

    for (int i = tid; i < 2 * 16 * HROW; i += 256) ((short*)hbuf)[i] = 0;
    __syncthreads();

    short8 BH00, BH01, BH10, BH11, BH20, BH21, BH30, BH31;
    short8 BX00, BX01, BX10, BX11, BX20, BX21, BX30, BX31;
    LOADB(BH00, 0, 0); LOADB(BH01, 0, 1); LOADB(BX00, 0, 2); LOADB(BX01, 0, 3);
    LOADB(BH10, 1, 0); LOADB(BH11, 1, 1); LOADB(BX10, 1, 2); LOADB(BX11, 1, 3);
    LOADB(BH20, 2, 0); LOADB(BH21, 2, 1); LOADB(BX20, 2, 2); LOADB(BX21, 2, 3);
    LOADB(BH30, 3, 0); LOADB(BH31, 3, 1); LOADB(BX30, 3, 2); LOADB(BX31, 3, 3);

    // Dense B-fragment: column 0 = dw, all other columns 0.
    short8 BD0, BD1;
    {
        short8 v0 = {0, 0, 0, 0, 0, 0, 0, 0}, v1 = v0;
        if (m == 0) {
#pragma unroll
            for (int i = 0; i < 8; ++i) v0[i] = (short)f2bf(dw[(q << 3) + i]);
#pragma unroll
            for (int i = 0; i < 8; ++i) v1[i] = (short)f2bf(dw[32 + (q << 3) + i]);
        }
        BD0 = v0; BD1 = v1;
    }

    const float b0 = bias[n0], b1 = bias[64 + n0];
    const float b2 = bias[128 + n0], b3 = bias[192 + n0];
    const f32x4 cb0 = {b0, b0, b0, b0};
    const f32x4 cb1 = {b1, b1, b1, b1};
    const f32x4 cb2 = {b2, b2, b2, b2};
    const f32x4 cb3 = {b3, b3, b3, b3};
    const float db0 = db[0];

    // x addressing: A-row m <- batch-in-block m>>2 (each batch dup x4; pad
    // lanes' z regs are never consumed).
    const int mb  = bb >> 2;
    const int l16 = ((bb & 3) << 2) | (m >> 2); // row within 16-row macroblock
    const size_t xb0 = (size_t)mb * 131072 + (size_t)(((l16 << 2) | q) << 1);

    const short8* __restrict__ xsrc = (const short8*)xA;
    short8 X00 = xsrc[XIDX(0)], X01 = xsrc[XIDX(0) + 1];
    short8 X10 = xsrc[XIDX(1)], X11 = xsrc[XIDX(1) + 1];
    short8 X20 = xsrc[XIDX(2)], X21 = xsrc[XIDX(2) + 1];
    short8 X30 = xsrc[XIDX(3)], X31 = xsrc[XIDX(3) + 1];

    // xpart for t=0 (set A)
    f32x4 qA0 = MF(X01, BX01, MF(X00, BX00, cb0));
    f32x4 qA1 = MF(X01, BX11, MF(X00, BX10, cb1));
    f32x4 qA2 = MF(X01, BX21, MF(X00, BX20, cb2));
    f32x4 qA3 = MF(X01, BX31, MF(X00, BX30, cb3));
    f32x4 qB0, qB1, qB2, qB3;

    float cc0 = 0.f;

    REGION(0, 0, X00, X01, X10, X11, qA0, qA1, qA2, qA3, qB0, qB1, qB2, qB3, 0);
    REGION(1, 1, X10, X11, X20, X21, qB0, qB1, qB2, qB3, qA0, qA1, qA2, qA3, 1);
    REGION(2, 0, X20, X21, X30, X31, qA0, qA1, qA2, qA3, qB0, qB1, qB2, qB3, 1);
    REGION(3, 1, X30, X31, X00, X01, qB0, qB1, qB2, qB3, qA0, qA1, qA2, qA3, 1);
    for (int t = 4; t < SS; t += 4) {
        REGION(t,     0, X00, X01, X10, X11, qA0, qA1, qA2, qA3, qB0, qB1, qB2, qB3, 1);
        REGION(t + 1, 1, X10, X11, X20, X21, qB0, qB1, qB2, qB3, qA0, qA1, qA2, qA3, 1);
        REGION(t + 2, 0, X20, X21, X30, X31, qA0, qA1, qA2, qA3, qB0, qB1, qB2, qB3, 1);
        REGION(t + 3, 1, X30, X31, X00, X01, qB0, qB1, qB2, qB3, qA0, qA1, qA2, qA3, 1);
    }
    // Epilogue: dense for h_{SS-1} (in hbuf[1] after the final barrier).
    if (w == 0) {
        const short8 ha0 = *(const short8*)&hbuf[1][m * HROW + (q << 3)];
        const short8 ha1 = *(const short8*)&hbuf[1][m * HROW + 32 + (q << 3)];
        const f32x4 zzero = {0.f, 0.f, 0.f, 0.f};
        const f32x4 z4 = MF(ha1, BD1, MF(ha0, BD0, zzero));
        if (m == 0) {
            out[((size_t)((bb << 2) + q) << 10) + SS - 1] =
                sigmoidf_(z4[0] + db0);
        }
    }
}

// ============ Host ============
extern "C" void kernel_launch(void* const* d_in, const int* in_sizes, int n_in,
                              void* d_out, int out_size, void* d_ws, size_t ws_size,
                              hipStream_t stream) {
    const float* x    = (const float*)d_in[0];
    const float* wk   = (const float*)d_in[1];
    const float* rk   = (const float*)d_in[2];
    const float* bias = (const float*)d_in[3];
    const float* dw   = (const float*)d_in[4];
    const float* db   = (const float*)d_in[5];
    float* out = (float*)d_out;

    short* xA = (short*)d_ws;   // 16*1024*128 short8 = 33.5 MB

    hipLaunchKernelGGL(xconv, dim3(NB * 1024 * 128 / 256), dim3(256), 0, stream,
                       x, xA);
    hipLaunchKernelGGL(lstm_pipe, dim3(NBLK), dim3(256), 0, stream,
                       xA, wk, rk, bias, dw, db, out);
}